// Round 1
// baseline (1711.875 us; speedup 1.0000x reference)
//
#include <hip/hip_runtime.h>

// ============================================================================
// Wired CfC (NCP) scan, B=256 x T=1024, 3 layers (hid 135/89/32) + final FC.
//
// Round 5: rounds 3/4 spilled ~70 dwords/lane (VGPR_Count=128 vs ~200 demand;
// WRITE_SIZE=68MB = one-time scratch writes; ~37TB of per-tick scratch
// reloads through L2 = the bottleneck). amdgpu_waves_per_eu(2,2) was ignored
// by the backend. Instead of fighting the budget heuristic, make the demand
// fit the budget that is STRUCTURAL: 1024-thread blocks force 4 waves/EU
// (a whole workgroup must be resident) -> 128-VGPR budget guaranteed.
// 4-way K-split: 4 lanes per output unit, 56 of KPAD=224 elems per lane ->
// weights 3 x 28 half2 = 84 VGPRs, total live ~110 < 128. Zero spill by
// construction.
//
// Design: persistent-RNN, 256 blocks x 1024 threads (1 batch row per block),
// output unit = tid>>2, K-quarter = tid&3.
//  - Weights (W1*mask, W2*mask, Wa+Wb) pre-folded to f16 pairs in VGPRs.
//  - Per tick: 7 x (ds_read_b128 broadcast + 12 v_dot2_f32_f16) per lane,
//    quad-combine via __shfl_xor(.,1)+__shfl_xor(.,2), fast tanh/sigmoid,
//    blend. Layers pipelined across timesteps -> ONE __syncthreads per tick.
//    Ping-pong f16 xcat in LDS. x prefetched 2 ahead by threads 960..1023.
// VALU floor ~832 cyc/tick/SIMD -> ~355us; predict 450-650us.
// ============================================================================

typedef _Float16 half2v __attribute__((ext_vector_type(2)));
typedef _Float16 half8v __attribute__((ext_vector_type(8)));

#define NBLK   256
#define NTHR   1024
#define TSTEPS 1024
#define KPAD   224
#define KQUAR  56
#define NKB    7       // KQUAR / 8 blocks per lane

struct Ptrs {
    const float* x;
    const unsigned int* msk[3];   // bool in reference -> int32 on device
    const float* W1[3];
    const float* W2[3];
    const float* Wa[3];
    const float* Wb[3];
    const float* b1[3];
    const float* b2[3];
    const float* ba[3];
    const float* bb[3];
    const float* fcW;
    const float* fcb;
};

__device__ __forceinline__ float fexp2(float x) {
#if __has_builtin(__builtin_amdgcn_exp2f)
    return __builtin_amdgcn_exp2f(x);
#else
    return exp2f(x);
#endif
}
__device__ __forceinline__ float frcp(float x) {
#if __has_builtin(__builtin_amdgcn_rcpf)
    return __builtin_amdgcn_rcpf(x);
#else
    return 1.0f / x;
#endif
}
// sigmoid(x) = 1/(1+2^(-x*log2e)); tanh(x) = 2/(1+2^(-2x*log2e)) - 1
__device__ __forceinline__ float fsig(float x) {
    return frcp(1.0f + fexp2(-1.442695041f * x));
}
__device__ __forceinline__ float ftanh(float x) {
    return 2.0f * frcp(1.0f + fexp2(-2.885390082f * x)) - 1.0f;
}

#if __has_builtin(__builtin_amdgcn_fdot2)
#define FD(a, b, c) __builtin_amdgcn_fdot2((a), (b), (c), false)
#else
__device__ __forceinline__ float fd_fallback(half2v a, half2v b, float c) {
    return c + (float)a[0] * (float)b[0] + (float)a[1] * (float)b[1];
}
#define FD(a, b, c) fd_fallback((a), (b), (c))
#endif

__global__ __launch_bounds__(NTHR)
void cfc_kernel(Ptrs P, float* __restrict__ out) {
    // xc[parity][layer][k] : f16 concat inputs per layer, zero-padded to KPAD.
    __shared__ __align__(16) _Float16 xc[2][3][KPAD];
    __shared__ __align__(16) float hn[256];

    const int tid  = threadIdx.x;
    const int b    = blockIdx.x;
    const int unit = tid >> 2;   // output unit 0..255
    const int q    = tid & 3;    // which K-quarter this lane owns

    // ---- unit role: which layer / which row ----
    int L, n;
    if (unit < 135)      { L = 0; n = unit; }
    else if (unit < 224) { L = 1; n = unit - 135; }
    else                 { L = 2; n = unit - 224; }
    const int K    = (L == 0) ? 199 : ((L == 1) ? 224 : 121);
    const int HOFF = (L == 0) ? 0   : ((L == 1) ? 135 : 224);

    // ---- zero LDS (padding regions must read as 0.0) ----
    {
        int* z = (int*)&xc[0][0][0];
        for (int i = tid; i < 2 * 3 * KPAD / 2; i += NTHR) z[i] = 0;
    }
    __syncthreads();

    // ---- x staging: threads 960..1023 own one of the 64 input features ----
    const int xlane = tid - (NTHR - 64);
    float xpend = 0.0f;
    if (xlane >= 0) {
        xc[0][0][xlane] = (_Float16)P.x[((size_t)b * TSTEPS + 0) * 64 + xlane];
        xpend           = P.x[((size_t)b * TSTEPS + 1) * 64 + xlane];
    }

    // ---- weight preload: this lane's K-quarter; fold mask, fold Wa+Wb; f16 ----
    const float* W1p        = P.W1[L];
    const float* W2p        = P.W2[L];
    const float* Wap        = P.Wa[L];
    const float* Wbp        = P.Wb[L];
    const unsigned int* mkp = P.msk[L];
    const int nK   = n * K;
    const int koff = q * KQUAR;

    half2v wr1[KQUAR / 2], wr2[KQUAR / 2], wra[KQUAR / 2];
#pragma unroll
    for (int i = 0; i < KQUAR / 2; ++i) {
        const int k0 = koff + 2 * i, k1 = koff + 2 * i + 1;
        float u0 = 0.f, u1 = 0.f, v0 = 0.f, v1 = 0.f, a0 = 0.f, a1 = 0.f;
        if (k0 < K) {
            const int idx = nK + k0;
            const float mm = (mkp[idx] != 0u) ? 1.0f : 0.0f;
            u0 = W1p[idx] * mm;
            v0 = W2p[idx] * mm;
            a0 = Wap[idx] + Wbp[idx];
        }
        if (k1 < K) {
            const int idx = nK + k1;
            const float mm = (mkp[idx] != 0u) ? 1.0f : 0.0f;
            u1 = W1p[idx] * mm;
            v1 = W2p[idx] * mm;
            a1 = Wap[idx] + Wbp[idx];
        }
        wr1[i] = half2v{(_Float16)u0, (_Float16)u1};
        wr2[i] = half2v{(_Float16)v0, (_Float16)v1};
        wra[i] = half2v{(_Float16)a0, (_Float16)a1};
    }
    const float bv1 = P.b1[L][n];
    const float bv2 = P.b2[L][n];
    const float bva = P.ba[L][n] + P.bb[L][n];
    __syncthreads();

    // ---- main scan: layer L computes timestep (tick - L); 1 barrier/tick ----
    for (int tick = 0; tick < TSTEPS + 2; ++tick) {
        // stage x(tick+1) (loaded 1 tick ago), prefetch x(tick+2)
        if (xlane >= 0) {
            if (tick + 1 < TSTEPS)
                xc[(tick + 1) & 1][0][xlane] = (_Float16)xpend;
            if (tick + 2 < TSTEPS)
                xpend = P.x[((size_t)b * TSTEPS + (tick + 2)) * 64 + xlane];
        }

        const int s = tick - L;
        if (s >= 0 && s < TSTEPS) {
            const _Float16* src = &xc[s & 1][L][koff];
            float ac00 = 0.f, ac01 = 0.f, ac10 = 0.f, ac11 = 0.f, ac20 = 0.f, ac21 = 0.f;
#pragma unroll
            for (int kb = 0; kb < NKB; ++kb) {
                const half8v xv = *(const half8v*)(src + kb * 8);
                const half2v x0 = {xv[0], xv[1]};
                const half2v x1 = {xv[2], xv[3]};
                const half2v x2 = {xv[4], xv[5]};
                const half2v x3 = {xv[6], xv[7]};
                const int k4 = kb * 4;
                ac00 = FD(x0, wr1[k4 + 0], ac00);
                ac10 = FD(x0, wr2[k4 + 0], ac10);
                ac20 = FD(x0, wra[k4 + 0], ac20);
                ac01 = FD(x1, wr1[k4 + 1], ac01);
                ac11 = FD(x1, wr2[k4 + 1], ac11);
                ac21 = FD(x1, wra[k4 + 1], ac21);
                ac00 = FD(x2, wr1[k4 + 2], ac00);
                ac10 = FD(x2, wr2[k4 + 2], ac10);
                ac20 = FD(x2, wra[k4 + 2], ac20);
                ac01 = FD(x3, wr1[k4 + 3], ac01);
                ac11 = FD(x3, wr2[k4 + 3], ac11);
                ac21 = FD(x3, wra[k4 + 3], ac21);
            }
            // combine the four K-quarters (quad = adjacent lanes in-wave)
            float s1 = ac00 + ac01;
            float s2 = ac10 + ac11;
            float sa = ac20 + ac21;
            s1 += __shfl_xor(s1, 1, 64);
            s2 += __shfl_xor(s2, 1, 64);
            sa += __shfl_xor(sa, 1, 64);
            s1 += __shfl_xor(s1, 2, 64);
            s2 += __shfl_xor(s2, 2, 64);
            sa += __shfl_xor(sa, 2, 64);
            // all four lanes now hold identical sums -> identical h
            const float f1 = ftanh(s1 + bv1);
            const float f2 = ftanh(s2 + bv2);
            const float tg = fsig(sa + bva);
            const float h  = f1 + tg * (f2 - f1);
            const _Float16 hv = (_Float16)h;

            const int pA = s & 1;        // consumer at timestep s (next layer)
            const int pB = (s + 1) & 1;  // consumer at timestep s+1 (own recurrence)
            // split the two stores across the quad
            if (q == 0) {
                if (L == 0)      xc[pA][1][n] = hv;        // -> layer1 input part
                else if (L == 1) xc[pA][2][n] = hv;        // -> layer2 input part
                if (s == TSTEPS - 1) hn[HOFF + n] = h;     // fp32 final state
            } else if (q == 1) {
                if (L == 0)      xc[pB][0][64 + n]  = hv;  // own recurrence
                else if (L == 1) xc[pB][1][135 + n] = hv;
                else             xc[pB][2][89 + n]  = hv;
            }
        }
        __syncthreads();
    }

    // ---- FC epilogue: out[b][o] = dot(hn, fcW[o,:]) + fcb[o], K-split quad ----
    {
        const int o = unit;
        const float4* wr = (const float4*)(P.fcW + (size_t)o * 256 + q * 64);
        const float4* hr = (const float4*)(hn + q * 64);
        float acc = (q == 0) ? P.fcb[o] : 0.0f;
#pragma unroll
        for (int d = 0; d < 16; ++d) {
            const float4 a = hr[d];
            const float4 w = wr[d];
            acc += a.x * w.x + a.y * w.y + a.z * w.z + a.w * w.w;
        }
        acc += __shfl_xor(acc, 1, 64);
        acc += __shfl_xor(acc, 2, 64);
        if (q == 0) out[(size_t)b * 256 + o] = acc;
    }
}

extern "C" void kernel_launch(void* const* d_in, const int* in_sizes, int n_in,
                              void* d_out, int out_size, void* d_ws, size_t ws_size,
                              hipStream_t stream) {
    (void)in_sizes; (void)n_in; (void)out_size; (void)d_ws; (void)ws_size;
    Ptrs P;
    P.x = (const float*)d_in[0];
    for (int l = 0; l < 3; ++l) {
        const int base = 1 + l * 9;
        P.msk[l] = (const unsigned int*)d_in[base + 0];
        P.W1[l]  = (const float*)d_in[base + 1];
        P.W2[l]  = (const float*)d_in[base + 2];
        P.Wa[l]  = (const float*)d_in[base + 3];
        P.Wb[l]  = (const float*)d_in[base + 4];
        P.b1[l]  = (const float*)d_in[base + 5];
        P.b2[l]  = (const float*)d_in[base + 6];
        P.ba[l]  = (const float*)d_in[base + 7];
        P.bb[l]  = (const float*)d_in[base + 8];
    }
    P.fcW = (const float*)d_in[28];
    P.fcb = (const float*)d_in[29];

    hipLaunchKernelGGL(cfc_kernel, dim3(NBLK), dim3(NTHR), 0, stream,
                       P, (float*)d_out);
}

// Round 2
// 1670.209 us; speedup vs baseline: 1.0249x; 1.0249x over previous
//
#include <hip/hip_runtime.h>

// ============================================================================
// Wired CfC (NCP) scan, B=256 x T=1024, 3 layers (hid 135/89/32) + final FC.
//
// Round 6: rounds 3-5 all spilled because the backend budgets VGPRs for
// TWO workgroups per CU by default (512thr->128 VGPR, 1024thr->64 VGPR),
// even though grid=256 on 256 CUs means exactly one block/CU. At a 64-VGPR
// budget vs ~110 demand, ~46 dwords/lane live in scratch; per-tick reloads
// (~49 TB via L2/L3) are the bottleneck (VALUBusy 63%, WRITE_SIZE 70MB of
// spill stores). Fix the BUDGET, not the demand:
//   1. __launch_bounds__(1024, 4): 2nd arg = min waves/EU = 4 -> exactly
//      one 16-wave workgroup per CU -> 128-VGPR budget.
//   2. 88 KiB static LDS (DCE-guarded, never touched): makes a second
//      workgroup per CU physically impossible (176KiB > 160KiB), so the
//      occupancy-derived default budget must also be 4 waves/EU. Free,
//      since no second block was ever co-resident anyway.
// Demand ~110 <= 128 -> zero spill. Expect WRITE_SIZE 70MB -> <2MB.
//
// Design: persistent-RNN, 256 blocks x 1024 threads (1 batch row per block),
// output unit = tid>>2, K-quarter = tid&3 (56 of KPAD=224 per lane).
//  - Weights (W1*mask, W2*mask, Wa+Wb) pre-folded to f16 pairs in VGPRs.
//  - Per tick: 7 x (ds_read_b128 broadcast + 12 v_dot2_f32_f16) per lane,
//    quad-combine via __shfl_xor(.,1)+__shfl_xor(.,2), fast tanh/sigmoid,
//    blend. Layers pipelined across timesteps -> ONE __syncthreads per tick.
//    Ping-pong f16 xcat in LDS. x prefetched 2 ahead by threads 960..1023.
// VALU floor ~672 cyc/SIMD/tick -> ~290us; predict 420-650us.
// ============================================================================

typedef _Float16 half2v __attribute__((ext_vector_type(2)));
typedef _Float16 half8v __attribute__((ext_vector_type(8)));

#define NBLK   256
#define NTHR   1024
#define TSTEPS 1024
#define KPAD   224
#define KQUAR  56
#define NKB    7       // KQUAR / 8 blocks per lane

struct Ptrs {
    const float* x;
    const unsigned int* msk[3];   // bool in reference -> int32 on device
    const float* W1[3];
    const float* W2[3];
    const float* Wa[3];
    const float* Wb[3];
    const float* b1[3];
    const float* b2[3];
    const float* ba[3];
    const float* bb[3];
    const float* fcW;
    const float* fcb;
};

__device__ __forceinline__ float fexp2(float x) {
#if __has_builtin(__builtin_amdgcn_exp2f)
    return __builtin_amdgcn_exp2f(x);
#else
    return exp2f(x);
#endif
}
__device__ __forceinline__ float frcp(float x) {
#if __has_builtin(__builtin_amdgcn_rcpf)
    return __builtin_amdgcn_rcpf(x);
#else
    return 1.0f / x;
#endif
}
// sigmoid(x) = 1/(1+2^(-x*log2e)); tanh(x) = 2/(1+2^(-2x*log2e)) - 1
__device__ __forceinline__ float fsig(float x) {
    return frcp(1.0f + fexp2(-1.442695041f * x));
}
__device__ __forceinline__ float ftanh(float x) {
    return 2.0f * frcp(1.0f + fexp2(-2.885390082f * x)) - 1.0f;
}

#if __has_builtin(__builtin_amdgcn_fdot2)
#define FD(a, b, c) __builtin_amdgcn_fdot2((a), (b), (c), false)
#else
__device__ __forceinline__ float fd_fallback(half2v a, half2v b, float c) {
    return c + (float)a[0] * (float)b[0] + (float)a[1] * (float)b[1];
}
#define FD(a, b, c) fd_fallback((a), (b), (c))
#endif

__global__ __launch_bounds__(NTHR, 4)   // min 4 waves/EU == 1 wg/CU -> 128-VGPR budget
void cfc_kernel(Ptrs P, float* __restrict__ out) {
    // xc[parity][layer][k] : f16 concat inputs per layer, zero-padded to KPAD.
    __shared__ __align__(16) _Float16 xc[2][3][KPAD];
    __shared__ __align__(16) float hn[256];
    // Occupancy forcer: 88 KiB of LDS makes a 2nd workgroup per CU impossible
    // (2 x ~92KiB > 160KiB), so the register allocator's occupancy-derived
    // budget is 4 waves/EU = 128 VGPRs. Guarded store defeats DCE; the branch
    // is never taken at runtime (out is never null).
    __shared__ float lds_vgpr_budget_forcer[22528];

    const int tid  = threadIdx.x;
    const int b    = blockIdx.x;
    const int unit = tid >> 2;   // output unit 0..255
    const int q    = tid & 3;    // which K-quarter this lane owns

    if (__builtin_expect(out == nullptr, 0)) {
        ((volatile float*)lds_vgpr_budget_forcer)[tid] = 1.0f;
    }

    // ---- unit role: which layer / which row ----
    int L, n;
    if (unit < 135)      { L = 0; n = unit; }
    else if (unit < 224) { L = 1; n = unit - 135; }
    else                 { L = 2; n = unit - 224; }
    const int K    = (L == 0) ? 199 : ((L == 1) ? 224 : 121);
    const int HOFF = (L == 0) ? 0   : ((L == 1) ? 135 : 224);

    // ---- zero LDS (padding regions must read as 0.0) ----
    {
        int* z = (int*)&xc[0][0][0];
        for (int i = tid; i < 2 * 3 * KPAD / 2; i += NTHR) z[i] = 0;
    }
    __syncthreads();

    // ---- x staging: threads 960..1023 own one of the 64 input features ----
    const int xlane = tid - (NTHR - 64);
    float xpend = 0.0f;
    if (xlane >= 0) {
        xc[0][0][xlane] = (_Float16)P.x[((size_t)b * TSTEPS + 0) * 64 + xlane];
        xpend           = P.x[((size_t)b * TSTEPS + 1) * 64 + xlane];
    }

    // ---- weight preload: this lane's K-quarter; fold mask, fold Wa+Wb; f16 ----
    const float* W1p        = P.W1[L];
    const float* W2p        = P.W2[L];
    const float* Wap        = P.Wa[L];
    const float* Wbp        = P.Wb[L];
    const unsigned int* mkp = P.msk[L];
    const int nK   = n * K;
    const int koff = q * KQUAR;

    half2v wr1[KQUAR / 2], wr2[KQUAR / 2], wra[KQUAR / 2];
#pragma unroll
    for (int i = 0; i < KQUAR / 2; ++i) {
        const int k0 = koff + 2 * i, k1 = koff + 2 * i + 1;
        float u0 = 0.f, u1 = 0.f, v0 = 0.f, v1 = 0.f, a0 = 0.f, a1 = 0.f;
        if (k0 < K) {
            const int idx = nK + k0;
            const float mm = (mkp[idx] != 0u) ? 1.0f : 0.0f;
            u0 = W1p[idx] * mm;
            v0 = W2p[idx] * mm;
            a0 = Wap[idx] + Wbp[idx];
        }
        if (k1 < K) {
            const int idx = nK + k1;
            const float mm = (mkp[idx] != 0u) ? 1.0f : 0.0f;
            u1 = W1p[idx] * mm;
            v1 = W2p[idx] * mm;
            a1 = Wap[idx] + Wbp[idx];
        }
        wr1[i] = half2v{(_Float16)u0, (_Float16)u1};
        wr2[i] = half2v{(_Float16)v0, (_Float16)v1};
        wra[i] = half2v{(_Float16)a0, (_Float16)a1};
    }
    const float bv1 = P.b1[L][n];
    const float bv2 = P.b2[L][n];
    const float bva = P.ba[L][n] + P.bb[L][n];
    __syncthreads();

    // ---- main scan: layer L computes timestep (tick - L); 1 barrier/tick ----
    for (int tick = 0; tick < TSTEPS + 2; ++tick) {
        // stage x(tick+1) (loaded 1 tick ago), prefetch x(tick+2)
        if (xlane >= 0) {
            if (tick + 1 < TSTEPS)
                xc[(tick + 1) & 1][0][xlane] = (_Float16)xpend;
            if (tick + 2 < TSTEPS)
                xpend = P.x[((size_t)b * TSTEPS + (tick + 2)) * 64 + xlane];
        }

        const int s = tick - L;
        if (s >= 0 && s < TSTEPS) {
            const _Float16* src = &xc[s & 1][L][koff];
            float ac00 = 0.f, ac01 = 0.f, ac10 = 0.f, ac11 = 0.f, ac20 = 0.f, ac21 = 0.f;
#pragma unroll
            for (int kb = 0; kb < NKB; ++kb) {
                const half8v xv = *(const half8v*)(src + kb * 8);
                const half2v x0 = {xv[0], xv[1]};
                const half2v x1 = {xv[2], xv[3]};
                const half2v x2 = {xv[4], xv[5]};
                const half2v x3 = {xv[6], xv[7]};
                const int k4 = kb * 4;
                ac00 = FD(x0, wr1[k4 + 0], ac00);
                ac10 = FD(x0, wr2[k4 + 0], ac10);
                ac20 = FD(x0, wra[k4 + 0], ac20);
                ac01 = FD(x1, wr1[k4 + 1], ac01);
                ac11 = FD(x1, wr2[k4 + 1], ac11);
                ac21 = FD(x1, wra[k4 + 1], ac21);
                ac00 = FD(x2, wr1[k4 + 2], ac00);
                ac10 = FD(x2, wr2[k4 + 2], ac10);
                ac20 = FD(x2, wra[k4 + 2], ac20);
                ac01 = FD(x3, wr1[k4 + 3], ac01);
                ac11 = FD(x3, wr2[k4 + 3], ac11);
                ac21 = FD(x3, wra[k4 + 3], ac21);
            }
            // combine the four K-quarters (quad = adjacent lanes in-wave)
            float s1 = ac00 + ac01;
            float s2 = ac10 + ac11;
            float sa = ac20 + ac21;
            s1 += __shfl_xor(s1, 1, 64);
            s2 += __shfl_xor(s2, 1, 64);
            sa += __shfl_xor(sa, 1, 64);
            s1 += __shfl_xor(s1, 2, 64);
            s2 += __shfl_xor(s2, 2, 64);
            sa += __shfl_xor(sa, 2, 64);
            // all four lanes now hold identical sums -> identical h
            const float f1 = ftanh(s1 + bv1);
            const float f2 = ftanh(s2 + bv2);
            const float tg = fsig(sa + bva);
            const float h  = f1 + tg * (f2 - f1);
            const _Float16 hv = (_Float16)h;

            const int pA = s & 1;        // consumer at timestep s (next layer)
            const int pB = (s + 1) & 1;  // consumer at timestep s+1 (own recurrence)
            // split the two stores across the quad
            if (q == 0) {
                if (L == 0)      xc[pA][1][n] = hv;        // -> layer1 input part
                else if (L == 1) xc[pA][2][n] = hv;        // -> layer2 input part
                if (s == TSTEPS - 1) hn[HOFF + n] = h;     // fp32 final state
            } else if (q == 1) {
                if (L == 0)      xc[pB][0][64 + n]  = hv;  // own recurrence
                else if (L == 1) xc[pB][1][135 + n] = hv;
                else             xc[pB][2][89 + n]  = hv;
            }
        }
        __syncthreads();
    }

    // ---- FC epilogue: out[b][o] = dot(hn, fcW[o,:]) + fcb[o], K-split quad ----
    {
        const int o = unit;
        const float4* wr = (const float4*)(P.fcW + (size_t)o * 256 + q * 64);
        const float4* hr = (const float4*)(hn + q * 64);
        float acc = (q == 0) ? P.fcb[o] : 0.0f;
#pragma unroll
        for (int d = 0; d < 16; ++d) {
            const float4 a = hr[d];
            const float4 w = wr[d];
            acc += a.x * w.x + a.y * w.y + a.z * w.z + a.w * w.w;
        }
        acc += __shfl_xor(acc, 1, 64);
        acc += __shfl_xor(acc, 2, 64);
        if (q == 0) out[(size_t)b * 256 + o] = acc;
    }
}

extern "C" void kernel_launch(void* const* d_in, const int* in_sizes, int n_in,
                              void* d_out, int out_size, void* d_ws, size_t ws_size,
                              hipStream_t stream) {
    (void)in_sizes; (void)n_in; (void)out_size; (void)d_ws; (void)ws_size;
    Ptrs P;
    P.x = (const float*)d_in[0];
    for (int l = 0; l < 3; ++l) {
        const int base = 1 + l * 9;
        P.msk[l] = (const unsigned int*)d_in[base + 0];
        P.W1[l]  = (const float*)d_in[base + 1];
        P.W2[l]  = (const float*)d_in[base + 2];
        P.Wa[l]  = (const float*)d_in[base + 3];
        P.Wb[l]  = (const float*)d_in[base + 4];
        P.b1[l]  = (const float*)d_in[base + 5];
        P.b2[l]  = (const float*)d_in[base + 6];
        P.ba[l]  = (const float*)d_in[base + 7];
        P.bb[l]  = (const float*)d_in[base + 8];
    }
    P.fcW = (const float*)d_in[28];
    P.fcb = (const float*)d_in[29];

    hipLaunchKernelGGL(cfc_kernel, dim3(NBLK), dim3(NTHR), 0, stream,
                       P, (float*)d_out);
}